// Round 17
// baseline (45.251 us; speedup 1.0000x reference)
//
#include <hip/hip_runtime.h>

namespace {

constexpr float kDT = 1e-3f;
constexpr int kB = 512;
constexpr int kT = 8192;
constexpr int kThreads = 1024;
constexpr int kWaves = kThreads / 64;   // 16
constexpr int kSub = kT / kThreads;     // 8 sub-passes, 1 step/thread each

// Affine transform x' = M x + b packed {a,b,c,d,p,q}
struct Xf { float a, b, c, d, p, q; };

__device__ __forceinline__ Xf comp(const Xf& e, const Xf& l) {
  Xf o;
  o.a = l.a * e.a + l.b * e.c;
  o.b = l.a * e.b + l.b * e.d;
  o.c = l.c * e.a + l.d * e.c;
  o.d = l.c * e.b + l.d * e.d;
  o.p = l.a * e.p + l.b * e.q + l.p;
  o.q = l.c * e.p + l.d * e.q + l.q;
  return o;
}

template <int Ctrl, int RowMask>
__device__ __forceinline__ float dpp1(float v, float old) {
  return __int_as_float(__builtin_amdgcn_update_dpp(
      __float_as_int(old), __float_as_int(v), Ctrl, RowMask, 0xf, false));
}

template <int Ctrl, int RowMask>
__device__ __forceinline__ Xf dpp_xf(const Xf& v) {
  Xf r;
  r.a = dpp1<Ctrl, RowMask>(v.a, 1.0f);
  r.b = dpp1<Ctrl, RowMask>(v.b, 0.0f);
  r.c = dpp1<Ctrl, RowMask>(v.c, 0.0f);
  r.d = dpp1<Ctrl, RowMask>(v.d, 1.0f);
  r.p = dpp1<Ctrl, RowMask>(v.p, 0.0f);
  r.q = dpp1<Ctrl, RowMask>(v.q, 0.0f);
  return r;
}

__device__ __forceinline__ Xf wave_incl_scan(Xf x) {
  x = comp(dpp_xf<0x111, 0xf>(x), x);  // row_shr:1
  x = comp(dpp_xf<0x112, 0xf>(x), x);  // row_shr:2
  x = comp(dpp_xf<0x114, 0xf>(x), x);  // row_shr:4
  x = comp(dpp_xf<0x118, 0xf>(x), x);  // row_shr:8
  x = comp(dpp_xf<0x142, 0xa>(x), x);  // row_bcast:15 -> rows 1,3
  x = comp(dpp_xf<0x143, 0xc>(x), x);  // row_bcast:31 -> rows 2,3
  return x;
}

__device__ __forceinline__ Xf readlane_xf(const Xf& v, int l) {
  Xf r;
  r.a = __int_as_float(__builtin_amdgcn_readlane(__float_as_int(v.a), l));
  r.b = __int_as_float(__builtin_amdgcn_readlane(__float_as_int(v.b), l));
  r.c = __int_as_float(__builtin_amdgcn_readlane(__float_as_int(v.c), l));
  r.d = __int_as_float(__builtin_amdgcn_readlane(__float_as_int(v.d), l));
  r.p = __int_as_float(__builtin_amdgcn_readlane(__float_as_int(v.p), l));
  r.q = __int_as_float(__builtin_amdgcn_readlane(__float_as_int(v.q), l));
  return r;
}

__device__ __forceinline__ Xf make_xf(const float4 xv, float d0, float d1,
                                      float A00, float A01, float A10, float A11,
                                      float C00, float C01, float C10, float C11) {
  Xf m;
  m.a = 1.0f + kDT * (A00 - (xv.x * C00 + xv.y * C10));
  m.b =        kDT * (A01 - (xv.x * C01 + xv.y * C11));
  m.c =        kDT * (A10 - (xv.z * C00 + xv.w * C10));
  m.d = 1.0f + kDT * (A11 - (xv.z * C01 + xv.w * C11));
  m.p = xv.x * d0 + xv.y * d1;
  m.q = xv.z * d0 + xv.w * d1;
  return m;
}

// One block per row; 8 sub-passes of 1024 steps, ONE step per thread
// (strided ownership: thread t owns step s*1024+t). Every global access is
// perfectly dense: xic float4 @16B/lane, dy/out float2 @8B/lane. DPP scans,
// double-buffered wave-total LDS, one barrier per sub-pass, 1-ahead prefetch.
__global__ __launch_bounds__(kThreads) void k_fused(
    const float* __restrict__ xic, const float* __restrict__ dy,
    const float* __restrict__ Ap, const float* __restrict__ Cp,
    float* __restrict__ out) {
  __shared__ float sWT[2][kWaves][6];

  const int tid = threadIdx.x;
  const int lane = tid & 63;
  const int w = tid >> 6;
  const size_t rbase = (size_t)blockIdx.x * kT;   // step index base

  const float4* X4 = reinterpret_cast<const float4*>(xic);
  const float2* D2 = reinterpret_cast<const float2*>(dy);
  float2* O2 = reinterpret_cast<float2*>(out);

  const float A00 = Ap[0], A01 = Ap[1], A10 = Ap[2], A11 = Ap[3];
  const float C00 = Cp[0], C01 = Cp[1], C10 = Cp[2], C11 = Cp[3];

  float4 xv[2];
  float2 dv[2];

  // Prefetch sub-pass 0 (perfectly coalesced).
  xv[0] = X4[rbase + tid];
  dv[0] = D2[rbase + tid];

  float x0 = 1.0f, x1 = 0.0f;  // row state entering current sub-pass

#pragma unroll
  for (int s = 0; s < kSub; ++s) {
    const int buf = s & 1;
    // Prefetch next sub-pass before any barrier/scan of this one.
    if (s + 1 < kSub) {
      const size_t nb = rbase + (size_t)(s + 1) * kThreads + tid;
      xv[buf ^ 1] = X4[nb];
      dv[buf ^ 1] = D2[nb];
    }

    // This thread's single step transform.
    const Xf m = make_xf(xv[buf], dv[buf].x, dv[buf].y,
                         A00, A01, A10, A11, C00, C01, C10, C11);

    // Wave-level inclusive scan (pure VALU/DPP).
    const Xf inc = wave_incl_scan(m);
    // Lane-exclusive prefix: whole-wave shift right by 1 (WF_SR1).
    const Xf le = dpp_xf<0x138, 0xf>(inc);

    if (lane == 63) {
      sWT[buf][w][0] = inc.a; sWT[buf][w][1] = inc.b; sWT[buf][w][2] = inc.c;
      sWT[buf][w][3] = inc.d; sWT[buf][w][4] = inc.p; sWT[buf][w][5] = inc.q;
    }
    __syncthreads();  // one barrier per sub-pass (sWT double-buffered)

    // Every wave: lanes 0..15 read the 16 wave totals, 4-round DPP scan.
    Xf v{1.f, 0.f, 0.f, 1.f, 0.f, 0.f};
    if (lane < kWaves) {
      v = Xf{sWT[buf][lane][0], sWT[buf][lane][1], sWT[buf][lane][2],
             sWT[buf][lane][3], sWT[buf][lane][4], sWT[buf][lane][5]};
    }
    v = comp(dpp_xf<0x111, 0xf>(v), v);
    v = comp(dpp_xf<0x112, 0xf>(v), v);
    v = comp(dpp_xf<0x114, 0xf>(v), v);
    v = comp(dpp_xf<0x118, 0xf>(v), v);

    const Xf TT = readlane_xf(v, kWaves - 1);   // sub-pass total
    Xf Ew{1.f, 0.f, 0.f, 1.f, 0.f, 0.f};
    if (w > 0) Ew = readlane_xf(v, w - 1);      // wave-uniform branch

    const Xf ex = comp(Ew, le);  // block-exclusive prefix for this thread

    // State entering this thread's step; emit (pre-update state).
    const float e0 = ex.a * x0 + ex.b * x1 + ex.p;
    const float e1 = ex.c * x0 + ex.d * x1 + ex.q;
    float2 o;
    o.x = kDT * (C00 * e0 + C01 * e1);
    o.y = kDT * (C10 * e0 + C11 * e1);
    O2[rbase + (size_t)s * kThreads + tid] = o;

    // Advance row state by the whole sub-pass (identical in all threads).
    if (s + 1 < kSub) {
      const float n0 = TT.a * x0 + TT.b * x1 + TT.p;
      const float n1 = TT.c * x0 + TT.d * x1 + TT.q;
      x0 = n0; x1 = n1;
    }
  }
}

}  // namespace

extern "C" void kernel_launch(void* const* d_in, const int* in_sizes, int n_in,
                              void* d_out, int out_size, void* d_ws,
                              size_t ws_size, hipStream_t stream) {
  const float* xic = (const float*)d_in[0];  // [B,T,2,2]
  const float* dy  = (const float*)d_in[1];  // [B,T,2]
  const float* Ap  = (const float*)d_in[2];  // [2,2] coeffs_A
  const float* Cp  = (const float*)d_in[3];  // [2,2] C
  float* out = (float*)d_out;                // [B,T,2]

  k_fused<<<kB, kThreads, 0, stream>>>(xic, dy, Ap, Cp, out);
}

// Round 18
// 30.514 us; speedup vs baseline: 1.4829x; 1.4829x over previous
//
#include <hip/hip_runtime.h>

namespace {

constexpr float kDT = 1e-3f;
constexpr int kB = 512;
constexpr int kT = 8192;
constexpr int kThreads = 1024;
constexpr int kWaves = kThreads / 64;   // 16
constexpr int kSub = 4;                 // sub-passes; 2 consecutive steps each

// Affine transform x' = M x + b packed {a,b,c,d,p,q}
struct Xf { float a, b, c, d, p, q; };

__device__ __forceinline__ Xf comp(const Xf& e, const Xf& l) {
  Xf o;
  o.a = l.a * e.a + l.b * e.c;
  o.b = l.a * e.b + l.b * e.d;
  o.c = l.c * e.a + l.d * e.c;
  o.d = l.c * e.b + l.d * e.d;
  o.p = l.a * e.p + l.b * e.q + l.p;
  o.q = l.c * e.p + l.d * e.q + l.q;
  return o;
}

template <int Ctrl, int RowMask>
__device__ __forceinline__ float dpp1(float v, float old) {
  return __int_as_float(__builtin_amdgcn_update_dpp(
      __float_as_int(old), __float_as_int(v), Ctrl, RowMask, 0xf, false));
}

template <int Ctrl, int RowMask>
__device__ __forceinline__ Xf dpp_xf(const Xf& v) {
  Xf r;
  r.a = dpp1<Ctrl, RowMask>(v.a, 1.0f);
  r.b = dpp1<Ctrl, RowMask>(v.b, 0.0f);
  r.c = dpp1<Ctrl, RowMask>(v.c, 0.0f);
  r.d = dpp1<Ctrl, RowMask>(v.d, 1.0f);
  r.p = dpp1<Ctrl, RowMask>(v.p, 0.0f);
  r.q = dpp1<Ctrl, RowMask>(v.q, 0.0f);
  return r;
}

__device__ __forceinline__ Xf wave_incl_scan(Xf x) {
  x = comp(dpp_xf<0x111, 0xf>(x), x);  // row_shr:1
  x = comp(dpp_xf<0x112, 0xf>(x), x);  // row_shr:2
  x = comp(dpp_xf<0x114, 0xf>(x), x);  // row_shr:4
  x = comp(dpp_xf<0x118, 0xf>(x), x);  // row_shr:8
  x = comp(dpp_xf<0x142, 0xa>(x), x);  // row_bcast:15 -> rows 1,3
  x = comp(dpp_xf<0x143, 0xc>(x), x);  // row_bcast:31 -> rows 2,3
  return x;
}

__device__ __forceinline__ Xf readlane_xf(const Xf& v, int l) {
  Xf r;
  r.a = __int_as_float(__builtin_amdgcn_readlane(__float_as_int(v.a), l));
  r.b = __int_as_float(__builtin_amdgcn_readlane(__float_as_int(v.b), l));
  r.c = __int_as_float(__builtin_amdgcn_readlane(__float_as_int(v.c), l));
  r.d = __int_as_float(__builtin_amdgcn_readlane(__float_as_int(v.d), l));
  r.p = __int_as_float(__builtin_amdgcn_readlane(__float_as_int(v.p), l));
  r.q = __int_as_float(__builtin_amdgcn_readlane(__float_as_int(v.q), l));
  return r;
}

__device__ __forceinline__ Xf make_xf(const float4 xv, float d0, float d1,
                                      float A00, float A01, float A10, float A11,
                                      float C00, float C01, float C10, float C11) {
  Xf m;
  m.a = 1.0f + kDT * (A00 - (xv.x * C00 + xv.y * C10));
  m.b =        kDT * (A01 - (xv.x * C01 + xv.y * C11));
  m.c =        kDT * (A10 - (xv.z * C00 + xv.w * C10));
  m.d = 1.0f + kDT * (A11 - (xv.z * C01 + xv.w * C11));
  m.p = xv.x * d0 + xv.y * d1;
  m.q = xv.z * d0 + xv.w * d1;
  return m;
}

// One block per row, ONE barrier per row. Each thread: 4 sub-passes x 2
// consecutive steps (R12's load pattern), 4 INDEPENDENT wave scans (ILP),
// wave totals -> LDS[64], one barrier, one 64-wide DPP stitch scan gives
// every (sub,wave) its global-row prefix. No sequential pass state carry.
__global__ __launch_bounds__(kThreads) void k_fused(
    const float* __restrict__ xic, const float* __restrict__ dy,
    const float* __restrict__ Ap, const float* __restrict__ Cp,
    float* __restrict__ out) {
  __shared__ float sWT[kSub * kWaves][6];   // 64 (sub,wave) totals

  const int tid = threadIdx.x;
  const int lane = tid & 63;
  const int w = tid >> 6;
  const size_t rbase = (size_t)blockIdx.x * kT;        // xic float4 index
  const size_t rbase2 = (size_t)blockIdx.x * (kT / 2); // dy/out float4 index

  const float4* X4 = reinterpret_cast<const float4*>(xic);
  const float4* D4 = reinterpret_cast<const float4*>(dy);
  float4* O4 = reinterpret_cast<float4*>(out);

  const float A00 = Ap[0], A01 = Ap[1], A10 = Ap[2], A11 = Ap[3];
  const float C00 = Cp[0], C01 = Cp[1], C10 = Cp[2], C11 = Cp[3];

  // Issue ALL loads up front (12 independent loads in flight).
  float4 xa[kSub], xb[kSub], dv[kSub];
#pragma unroll
  for (int s = 0; s < kSub; ++s) {
    const size_t xi = rbase + (size_t)s * 2048 + 2 * tid;
    xa[s] = X4[xi];
    xb[s] = X4[xi + 1];
    dv[s] = D4[rbase2 + (size_t)s * 1024 + tid];
  }

  // 4 independent sub-pass scans (interleavable DPP chains).
  Xf s0v[kSub], lev[kSub];
#pragma unroll
  for (int s = 0; s < kSub; ++s) {
    s0v[s] = make_xf(xa[s], dv[s].x, dv[s].y,
                     A00, A01, A10, A11, C00, C01, C10, C11);
    const Xf s1 = make_xf(xb[s], dv[s].z, dv[s].w,
                          A00, A01, A10, A11, C00, C01, C10, C11);
    const Xf inc = wave_incl_scan(comp(s0v[s], s1));
    lev[s] = dpp_xf<0x138, 0xf>(inc);          // WF_SR1 lane-exclusive
    if (lane == 63) {
      float* o = sWT[s * kWaves + w];
      o[0] = inc.a; o[1] = inc.b; o[2] = inc.c;
      o[3] = inc.d; o[4] = inc.p; o[5] = inc.q;
    }
  }
  __syncthreads();   // the ONLY barrier

  // 64-wide stitch: lane holds total of (sub = lane>>4, wave = lane&15) --
  // chronological order == lane order. One full wave scan.
  Xf v{sWT[lane][0], sWT[lane][1], sWT[lane][2],
       sWT[lane][3], sWT[lane][4], sWT[lane][5]};
  v = wave_incl_scan(v);

  // Emit each sub-pass: global-row exclusive prefix = v[16s + w - 1] ∘ le.
#pragma unroll
  for (int s = 0; s < kSub; ++s) {
    const int idx = s * kWaves + w - 1;          // wave-uniform
    Xf Ew{1.f, 0.f, 0.f, 1.f, 0.f, 0.f};
    if (idx >= 0) Ew = readlane_xf(v, idx);
    const Xf ex = comp(Ew, lev[s]);

    // Row-initial state (1,0) -> state entering this thread's first step.
    float e0 = ex.a + ex.p;
    float e1 = ex.c + ex.q;

    float4 o;
    o.x = kDT * (C00 * e0 + C01 * e1);
    o.y = kDT * (C10 * e0 + C11 * e1);
    const float n0 = s0v[s].a * e0 + s0v[s].b * e1 + s0v[s].p;
    const float n1 = s0v[s].c * e0 + s0v[s].d * e1 + s0v[s].q;
    o.z = kDT * (C00 * n0 + C01 * n1);
    o.w = kDT * (C10 * n0 + C11 * n1);
    O4[rbase2 + (size_t)s * 1024 + tid] = o;
  }
}

}  // namespace

extern "C" void kernel_launch(void* const* d_in, const int* in_sizes, int n_in,
                              void* d_out, int out_size, void* d_ws,
                              size_t ws_size, hipStream_t stream) {
  const float* xic = (const float*)d_in[0];  // [B,T,2,2]
  const float* dy  = (const float*)d_in[1];  // [B,T,2]
  const float* Ap  = (const float*)d_in[2];  // [2,2] coeffs_A
  const float* Cp  = (const float*)d_in[3];  // [2,2] C
  float* out = (float*)d_out;                // [B,T,2]

  k_fused<<<kB, kThreads, 0, stream>>>(xic, dy, Ap, Cp, out);
}

// Round 20
// 29.590 us; speedup vs baseline: 1.5293x; 1.0312x over previous
//
#include <hip/hip_runtime.h>

namespace {

constexpr float kDT = 1e-3f;
constexpr int kB = 512;
constexpr int kT = 8192;
constexpr int kThreads = 1024;
constexpr int kWaves = kThreads / 64;     // 16
constexpr int kPassSteps = 2 * kThreads;  // 2048 steps per pass
constexpr int kPasses = kT / kPassSteps;  // 4

typedef float vfloat4 __attribute__((ext_vector_type(4)));  // native clang vec

// Affine transform x' = M x + b packed {a,b,c,d,p,q}
struct Xf { float a, b, c, d, p, q; };

__device__ __forceinline__ Xf comp(const Xf& e, const Xf& l) {
  Xf o;
  o.a = l.a * e.a + l.b * e.c;
  o.b = l.a * e.b + l.b * e.d;
  o.c = l.c * e.a + l.d * e.c;
  o.d = l.c * e.b + l.d * e.d;
  o.p = l.a * e.p + l.b * e.q + l.p;
  o.q = l.c * e.p + l.d * e.q + l.q;
  return o;
}

template <int Ctrl, int RowMask>
__device__ __forceinline__ float dpp1(float v, float old) {
  return __int_as_float(__builtin_amdgcn_update_dpp(
      __float_as_int(old), __float_as_int(v), Ctrl, RowMask, 0xf, false));
}

template <int Ctrl, int RowMask>
__device__ __forceinline__ Xf dpp_xf(const Xf& v) {
  Xf r;
  r.a = dpp1<Ctrl, RowMask>(v.a, 1.0f);
  r.b = dpp1<Ctrl, RowMask>(v.b, 0.0f);
  r.c = dpp1<Ctrl, RowMask>(v.c, 0.0f);
  r.d = dpp1<Ctrl, RowMask>(v.d, 1.0f);
  r.p = dpp1<Ctrl, RowMask>(v.p, 0.0f);
  r.q = dpp1<Ctrl, RowMask>(v.q, 0.0f);
  return r;
}

__device__ __forceinline__ Xf wave_incl_scan(Xf x) {
  x = comp(dpp_xf<0x111, 0xf>(x), x);  // row_shr:1
  x = comp(dpp_xf<0x112, 0xf>(x), x);  // row_shr:2
  x = comp(dpp_xf<0x114, 0xf>(x), x);  // row_shr:4
  x = comp(dpp_xf<0x118, 0xf>(x), x);  // row_shr:8
  x = comp(dpp_xf<0x142, 0xa>(x), x);  // row_bcast:15 -> rows 1,3
  x = comp(dpp_xf<0x143, 0xc>(x), x);  // row_bcast:31 -> rows 2,3
  return x;
}

__device__ __forceinline__ Xf readlane_xf(const Xf& v, int l) {
  Xf r;
  r.a = __int_as_float(__builtin_amdgcn_readlane(__float_as_int(v.a), l));
  r.b = __int_as_float(__builtin_amdgcn_readlane(__float_as_int(v.b), l));
  r.c = __int_as_float(__builtin_amdgcn_readlane(__float_as_int(v.c), l));
  r.d = __int_as_float(__builtin_amdgcn_readlane(__float_as_int(v.d), l));
  r.p = __int_as_float(__builtin_amdgcn_readlane(__float_as_int(v.p), l));
  r.q = __int_as_float(__builtin_amdgcn_readlane(__float_as_int(v.q), l));
  return r;
}

__device__ __forceinline__ Xf make_xf(const float4 xv, float d0, float d1,
                                      float A00, float A01, float A10, float A11,
                                      float C00, float C01, float C10, float C11) {
  Xf m;
  m.a = 1.0f + kDT * (A00 - (xv.x * C00 + xv.y * C10));
  m.b =        kDT * (A01 - (xv.x * C01 + xv.y * C11));
  m.c =        kDT * (A10 - (xv.z * C00 + xv.w * C10));
  m.d = 1.0f + kDT * (A11 - (xv.z * C01 + xv.w * C11));
  m.p = xv.x * d0 + xv.y * d1;
  m.q = xv.z * d0 + xv.w * d1;
  return m;
}

// R12 structure (best, 30.2 us): one block per row, 4 passes, 2 consecutive
// steps/thread, DPP scans, 1 barrier/pass, 1-ahead register prefetch.
// R20 change: NON-TEMPORAL output stores via native clang vector type
// (no L3 allocation; frees Infinity Cache path for the input stream).
__global__ __launch_bounds__(kThreads) void k_fused(
    const float* __restrict__ xic, const float* __restrict__ dy,
    const float* __restrict__ Ap, const float* __restrict__ Cp,
    float* __restrict__ out) {
  __shared__ float sWT[2][kWaves][6];

  const int tid = threadIdx.x;
  const int lane = tid & 63;
  const int w = tid >> 6;
  const size_t rbase = (size_t)blockIdx.x * kT;        // xic float4 index
  const size_t rbase2 = (size_t)blockIdx.x * (kT / 2); // dy/out float4 index

  const float4* X4 = reinterpret_cast<const float4*>(xic);
  const float4* D4 = reinterpret_cast<const float4*>(dy);
  vfloat4* O4 = reinterpret_cast<vfloat4*>(out);

  const float A00 = Ap[0], A01 = Ap[1], A10 = Ap[2], A11 = Ap[3];
  const float C00 = Cp[0], C01 = Cp[1], C10 = Cp[2], C11 = Cp[3];

  float4 xva[2], xvb[2], dva[2];

  // Prefetch pass 0.
  {
    const size_t s = (size_t)2 * tid;
    xva[0] = X4[rbase + s];
    xvb[0] = X4[rbase + s + 1];
    dva[0] = D4[rbase2 + tid];
  }

  float x0 = 1.0f, x1 = 0.0f;  // row state entering current pass

#pragma unroll
  for (int c = 0; c < kPasses; ++c) {
    const int buf = c & 1;
    // Prefetch next pass before any barrier/scan of this pass.
    if (c + 1 < kPasses) {
      const size_t s = (size_t)(c + 1) * kPassSteps + 2 * tid;
      xva[buf ^ 1] = X4[rbase + s];
      xvb[buf ^ 1] = X4[rbase + s + 1];
      dva[buf ^ 1] = D4[rbase2 + (size_t)(c + 1) * kThreads + tid];
    }

    const Xf s0 = make_xf(xva[buf], dva[buf].x, dva[buf].y,
                          A00, A01, A10, A11, C00, C01, C10, C11);
    const Xf s1 = make_xf(xvb[buf], dva[buf].z, dva[buf].w,
                          A00, A01, A10, A11, C00, C01, C10, C11);
    const Xf tot = comp(s0, s1);

    // Wave-level inclusive scan (pure VALU/DPP).
    const Xf inc = wave_incl_scan(tot);

    if (lane == 63) {
      sWT[buf][w][0] = inc.a; sWT[buf][w][1] = inc.b; sWT[buf][w][2] = inc.c;
      sWT[buf][w][3] = inc.d; sWT[buf][w][4] = inc.p; sWT[buf][w][5] = inc.q;
    }
    __syncthreads();  // one barrier per pass (sWT double-buffered)

    // Every wave: lanes 0..15 read the 16 wave totals, 4-round DPP scan.
    Xf v{1.f, 0.f, 0.f, 1.f, 0.f, 0.f};
    if (lane < kWaves) {
      v = Xf{sWT[buf][lane][0], sWT[buf][lane][1], sWT[buf][lane][2],
             sWT[buf][lane][3], sWT[buf][lane][4], sWT[buf][lane][5]};
    }
    v = comp(dpp_xf<0x111, 0xf>(v), v);
    v = comp(dpp_xf<0x112, 0xf>(v), v);
    v = comp(dpp_xf<0x114, 0xf>(v), v);
    v = comp(dpp_xf<0x118, 0xf>(v), v);

    const Xf TT = readlane_xf(v, kWaves - 1);           // pass total
    Xf Ew{1.f, 0.f, 0.f, 1.f, 0.f, 0.f};
    if (w > 0) Ew = readlane_xf(v, w - 1);              // wave-uniform branch

    // Lane-exclusive prefix: whole-wave shift right by 1 (WF_SR1).
    const Xf le = dpp_xf<0x138, 0xf>(inc);              // lane0 -> identity

    const Xf ex = comp(Ew, le);  // block-exclusive prefix for this thread

    const float e0 = ex.a * x0 + ex.b * x1 + ex.p;
    const float e1 = ex.c * x0 + ex.d * x1 + ex.q;

    vfloat4 o;
    o.x = kDT * (C00 * e0 + C01 * e1);
    o.y = kDT * (C10 * e0 + C11 * e1);
    const float t0 = s0.a * e0 + s0.b * e1 + s0.p;
    const float t1 = s0.c * e0 + s0.d * e1 + s0.q;
    o.z = kDT * (C00 * t0 + C01 * t1);
    o.w = kDT * (C10 * t0 + C11 * t1);
    // Non-temporal: stream to HBM, no L3 allocation.
    __builtin_nontemporal_store(o, &O4[rbase2 + (size_t)c * kThreads + tid]);

    if (c + 1 < kPasses) {
      const float n0 = TT.a * x0 + TT.b * x1 + TT.p;
      const float n1 = TT.c * x0 + TT.d * x1 + TT.q;
      x0 = n0; x1 = n1;
    }
  }
}

}  // namespace

extern "C" void kernel_launch(void* const* d_in, const int* in_sizes, int n_in,
                              void* d_out, int out_size, void* d_ws,
                              size_t ws_size, hipStream_t stream) {
  const float* xic = (const float*)d_in[0];  // [B,T,2,2]
  const float* dy  = (const float*)d_in[1];  // [B,T,2]
  const float* Ap  = (const float*)d_in[2];  // [2,2] coeffs_A
  const float* Cp  = (const float*)d_in[3];  // [2,2] C
  float* out = (float*)d_out;                // [B,T,2]

  k_fused<<<kB, kThreads, 0, stream>>>(xic, dy, Ap, Cp, out);
}